// Round 1
// baseline (124.930 us; speedup 1.0000x reference)
//
#include <hip/hip_runtime.h>
#include <hip/hip_bf16.h>

#define B 32
#define C 512
#define HW 3136            // 56*56
#define TH 0.01f

// ---------------------------------------------------------------------------
// Kernel 1: alpha[b,c] = mean over HW of x[b,c,:,:]
// One 256-thread block per (b,c). 3136 floats = 784 float4.
// ---------------------------------------------------------------------------
__global__ __launch_bounds__(256) void alpha_kernel(const float* __restrict__ x,
                                                    float* __restrict__ alpha) {
    const int bc = blockIdx.x;                 // 0 .. B*C-1
    const float4* xv = (const float4*)(x + (size_t)bc * HW);
    float s = 0.f;
    for (int i = threadIdx.x; i < HW / 4; i += 256) {
        float4 v = xv[i];
        s += (v.x + v.y) + (v.z + v.w);
    }
    // wave (64-lane) reduction
    #pragma unroll
    for (int off = 32; off > 0; off >>= 1) s += __shfl_down(s, off);
    __shared__ float red[4];
    const int lane = threadIdx.x & 63;
    const int wid  = threadIdx.x >> 6;
    if (lane == 0) red[wid] = s;
    __syncthreads();
    if (threadIdx.x == 0) {
        float t = (red[0] + red[1]) + (red[2] + red[3]);
        alpha[bc] = t * (1.0f / (float)HW);
    }
}

// ---------------------------------------------------------------------------
// Kernel 2: fused saliency + conv1x1 + relu/threshold + sigmoid epilogue.
// Block = 256 consecutive hw positions of one b.
//   sal[b,hw] = (1/C) * sum_c x[b,c,hw] * alpha[b,c]
//   out[b,co,hw] = 1 - wf * sigmoid(scale * (sal*w[co] > TH ? sal*w[co] : 0))
// ---------------------------------------------------------------------------
__global__ __launch_bounds__(256) void sal_out_kernel(const float* __restrict__ x,
                                                      const float* __restrict__ alpha,
                                                      const float* __restrict__ w,
                                                      const float* __restrict__ scale_p,
                                                      const float* __restrict__ wf_p,
                                                      float* __restrict__ out) {
    const int b  = blockIdx.y;
    const int hw = blockIdx.x * 256 + threadIdx.x;

    __shared__ float w_sm[C];
    __shared__ float a_sm[C];
    const float* arow = alpha + b * C;
    for (int i = threadIdx.x; i < C; i += 256) {
        w_sm[i] = w[i];
        a_sm[i] = arow[i];
    }
    __syncthreads();

    const size_t base = (size_t)b * C * HW;
    float sal = 0.f;
    if (hw < HW) {
        const float* xb = x + base + hw;
        #pragma unroll 8
        for (int c = 0; c < C; ++c) {
            sal += xb[(size_t)c * HW] * a_sm[c];
        }
    }
    sal *= (1.0f / (float)C);

    const float scale = scale_p[0];
    const float wf    = wf_p[0];
    const float out_zero = 1.0f - 0.5f * wf;   // fm == 0 path

    if (hw >= HW) return;

    float* ob = out + base + hw;
    #pragma unroll 4
    for (int co = 0; co < C; ++co) {
        float fm = sal * w_sm[co];
        float r;
        if (fm > TH) {
            float sig = 1.0f / (1.0f + __expf(-scale * fm));
            r = 1.0f - wf * sig;
        } else {
            r = out_zero;
        }
        ob[(size_t)co * HW] = r;
    }
}

extern "C" void kernel_launch(void* const* d_in, const int* in_sizes, int n_in,
                              void* d_out, int out_size, void* d_ws, size_t ws_size,
                              hipStream_t stream) {
    const float* x      = (const float*)d_in[0];
    const float* conv_w = (const float*)d_in[1];   // 512 floats
    const float* scale  = (const float*)d_in[2];
    const float* wf     = (const float*)d_in[3];
    float* out   = (float*)d_out;
    float* alpha = (float*)d_ws;                   // B*C floats = 64 KB

    alpha_kernel<<<B * C, 256, 0, stream>>>(x, alpha);

    dim3 grid2((HW + 255) / 256, B);
    sal_out_kernel<<<grid2, 256, 0, stream>>>(x, alpha, conv_w, scale, wf, out);
}

// Round 2
// 122.001 us; speedup vs baseline: 1.0240x; 1.0240x over previous
//
#include <hip/hip_runtime.h>
#include <hip/hip_bf16.h>

#define B 32
#define C 512
#define HW 3136            // 56*56
#define HW4 784            // HW/4
#define TH 0.01f

// ---------------------------------------------------------------------------
// Kernel 1: alpha[b,c] = mean over HW of x[b,c,:,:]
// One 256-thread block per (b,c). 3136 floats = 784 float4. HBM-read-bound.
// ---------------------------------------------------------------------------
__global__ __launch_bounds__(256) void alpha_kernel(const float* __restrict__ x,
                                                    float* __restrict__ alpha) {
    const int bc = blockIdx.x;                 // 0 .. B*C-1
    const float4* xv = (const float4*)(x + (size_t)bc * HW);
    float s = 0.f;
    for (int i = threadIdx.x; i < HW4; i += 256) {
        float4 v = xv[i];
        s += (v.x + v.y) + (v.z + v.w);
    }
    #pragma unroll
    for (int off = 32; off > 0; off >>= 1) s += __shfl_down(s, off);
    __shared__ float red[4];
    const int lane = threadIdx.x & 63;
    const int wid  = threadIdx.x >> 6;
    if (lane == 0) red[wid] = s;
    __syncthreads();
    if (threadIdx.x == 0) {
        float t = (red[0] + red[1]) + (red[2] + red[3]);
        alpha[bc] = t * (1.0f / (float)HW);
    }
}

// ---------------------------------------------------------------------------
// Kernel 2: sal[b,hw] = (1/C) * sum_c x[b,c,hw] * alpha[b,c]
// Block = 64 hw positions x 4 c-groups (256 threads). Grid = 49 x 32 = 1568.
// x is L3-resident after kernel 1 -> L3/L2-bound, short.
// ---------------------------------------------------------------------------
__global__ __launch_bounds__(256) void sal_kernel(const float* __restrict__ x,
                                                  const float* __restrict__ alpha,
                                                  float* __restrict__ sal) {
    const int b    = blockIdx.y;
    const int lane = threadIdx.x & 63;
    const int wid  = threadIdx.x >> 6;         // c-group 0..3
    const int hw   = blockIdx.x * 64 + lane;

    const float* __restrict__ arow = alpha + b * C;
    const float* __restrict__ xb   = x + (size_t)b * C * HW + hw;

    float s = 0.f;
    const int c0 = wid * 128;
    #pragma unroll 8
    for (int c = c0; c < c0 + 128; ++c) {
        s += xb[(size_t)c * HW] * arow[c];
    }

    __shared__ float red[4][64];
    red[wid][lane] = s;
    __syncthreads();
    if (threadIdx.x < 64) {
        float t = (red[0][threadIdx.x] + red[1][threadIdx.x]) +
                  (red[2][threadIdx.x] + red[3][threadIdx.x]);
        sal[b * HW + blockIdx.x * 64 + threadIdx.x] = t * (1.0f / (float)C);
    }
}

// ---------------------------------------------------------------------------
// Kernel 3: out[b,co,hw] = 1 - wf * sigmoid(scale * thresh(sal[b,hw]*w[co]))
// Pure streaming expansion: grid-stride over float4s, HBM-write-bound.
// ---------------------------------------------------------------------------
__global__ __launch_bounds__(256) void out_kernel(const float* __restrict__ sal,
                                                  const float* __restrict__ w,
                                                  const float* __restrict__ scale_p,
                                                  const float* __restrict__ wf_p,
                                                  float4* __restrict__ out) {
    const int N4 = B * C * HW4;                // 12,845,056 float4s
    const float scale = scale_p[0];
    const float wf    = wf_p[0];
    const float out_zero = 1.0f - 0.5f * wf;   // fm == 0 path

    for (int i = blockIdx.x * 256 + threadIdx.x; i < N4; i += gridDim.x * 256) {
        const int b   = i / (C * HW4);
        const int rem = i - b * (C * HW4);
        const int co  = rem / HW4;
        const int h4  = rem - co * HW4;

        const float4 s4 = ((const float4*)(sal + b * HW))[h4];
        const float  wc = w[co];

        float4 r;
        {
            float fm = s4.x * wc;
            r.x = (fm > TH) ? 1.0f - wf / (1.0f + __expf(-scale * fm)) : out_zero;
        }
        {
            float fm = s4.y * wc;
            r.y = (fm > TH) ? 1.0f - wf / (1.0f + __expf(-scale * fm)) : out_zero;
        }
        {
            float fm = s4.z * wc;
            r.z = (fm > TH) ? 1.0f - wf / (1.0f + __expf(-scale * fm)) : out_zero;
        }
        {
            float fm = s4.w * wc;
            r.w = (fm > TH) ? 1.0f - wf / (1.0f + __expf(-scale * fm)) : out_zero;
        }
        out[i] = r;
    }
}

extern "C" void kernel_launch(void* const* d_in, const int* in_sizes, int n_in,
                              void* d_out, int out_size, void* d_ws, size_t ws_size,
                              hipStream_t stream) {
    const float* x      = (const float*)d_in[0];
    const float* conv_w = (const float*)d_in[1];   // 512 floats
    const float* scale  = (const float*)d_in[2];
    const float* wf     = (const float*)d_in[3];
    float* out   = (float*)d_out;
    float* alpha = (float*)d_ws;                          // B*C floats = 64 KB
    float* sal   = (float*)d_ws + B * C;                  // B*HW floats = 401 KB

    alpha_kernel<<<B * C, 256, 0, stream>>>(x, alpha);

    dim3 grid2(HW / 64, B);                               // 49 x 32
    sal_kernel<<<grid2, 256, 0, stream>>>(x, alpha, sal);

    out_kernel<<<2048, 256, 0, stream>>>(sal, conv_w, scale, wf, (float4*)out);
}

// Round 4
// 106.887 us; speedup vs baseline: 1.1688x; 1.1414x over previous
//
#include <hip/hip_runtime.h>
#include <hip/hip_bf16.h>

#define B 32
#define C 512
#define HW 3136            // 56*56
#define HW4 784            // HW/4 float4 columns
#define TH 0.01f

typedef float fx4 __attribute__((ext_vector_type(4)));

// ---------------------------------------------------------------------------
// Kernel 1: alpha[b,c] = mean over HW of x[b,c,:,:]
// One 256-thread block per (b,c); pure HBM read pass, also warms L3 with x.
// ---------------------------------------------------------------------------
__global__ __launch_bounds__(256) void alpha_kernel(const float* __restrict__ x,
                                                    float* __restrict__ alpha) {
    const int bc = blockIdx.x;                 // 0 .. B*C-1
    const float4* xv = (const float4*)(x + (size_t)bc * HW);
    float s = 0.f;
    for (int i = threadIdx.x; i < HW4; i += 256) {
        float4 v = xv[i];
        s += (v.x + v.y) + (v.z + v.w);
    }
    #pragma unroll
    for (int off = 32; off > 0; off >>= 1) s += __shfl_down(s, off);
    __shared__ float red[4];
    if ((threadIdx.x & 63) == 0) red[threadIdx.x >> 6] = s;
    __syncthreads();
    if (threadIdx.x == 0) {
        alpha[bc] = ((red[0] + red[1]) + (red[2] + red[3])) * (1.0f / (float)HW);
    }
}

// ---------------------------------------------------------------------------
// Kernel 2: fused sal + conv1x1 + threshold + sigmoid + store.
// Block = (one b, 16 float4 hw-positions). Grid = 49 x 32 = 1568 blocks.
// Phase 1: sal4[hw4] = (1/C) sum_c x[b,c,hw4]*alpha[b,c]
//          (16 c-groups x 16 hw4 lanes; shfl_xor across c-groups in-wave,
//           LDS across the 4 waves). x reads should hit L3 (warmed by K1).
// Phase 2: for all 512 co: out = 1 - wf*sigmoid(scale*thresh(sal*w[co]))
//          nontemporal float4 stores -> don't evict x from L2/L3.
// ---------------------------------------------------------------------------
__global__ __launch_bounds__(256) void fused_kernel(const float* __restrict__ x,
                                                    const float* __restrict__ alpha,
                                                    const float* __restrict__ w,
                                                    const float* __restrict__ scale_p,
                                                    const float* __restrict__ wf_p,
                                                    float* __restrict__ out) {
    const int b    = blockIdx.y;
    const int tile = blockIdx.x;               // 0..48
    const int t    = threadIdx.x;
    const int hw4  = t & 15;                   // float4 column within tile
    const int cg   = t >> 4;                   // c-group 0..15 (32 c each)
    const int lane = t & 63;
    const int wid  = t >> 6;

    const float4* __restrict__ xb =
        (const float4*)(x + (size_t)b * C * HW) + tile * 16 + hw4;
    const float* __restrict__ arow = alpha + b * C;

    // ---- phase 1: c-reduction ----
    float4 acc = make_float4(0.f, 0.f, 0.f, 0.f);
    const int c0 = cg * 32;
    #pragma unroll 8
    for (int j = 0; j < 32; ++j) {
        const int c = c0 + j;
        float4 v = xb[(size_t)c * HW4];
        const float a = arow[c];
        acc.x += v.x * a; acc.y += v.y * a;
        acc.z += v.z * a; acc.w += v.w * a;
    }
    // reduce the 4 c-groups living in this wave (lane deltas 16, 32)
    acc.x += __shfl_xor(acc.x, 16); acc.y += __shfl_xor(acc.y, 16);
    acc.z += __shfl_xor(acc.z, 16); acc.w += __shfl_xor(acc.w, 16);
    acc.x += __shfl_xor(acc.x, 32); acc.y += __shfl_xor(acc.y, 32);
    acc.z += __shfl_xor(acc.z, 32); acc.w += __shfl_xor(acc.w, 32);

    __shared__ float4 red[4][16];
    if (lane < 16) red[wid][lane] = acc;
    __syncthreads();

    __shared__ float4 sal_sm[16];
    if (t < 16) {
        const float4 a0 = red[0][t], a1 = red[1][t], a2 = red[2][t], a3 = red[3][t];
        float4 s;
        s.x = ((a0.x + a1.x) + (a2.x + a3.x)) * (1.0f / (float)C);
        s.y = ((a0.y + a1.y) + (a2.y + a3.y)) * (1.0f / (float)C);
        s.z = ((a0.z + a1.z) + (a2.z + a3.z)) * (1.0f / (float)C);
        s.w = ((a0.w + a1.w) + (a2.w + a3.w)) * (1.0f / (float)C);
        sal_sm[t] = s;
    }
    __syncthreads();

    // ---- phase 2: expansion over co ----
    const float scale = scale_p[0];
    const float wf    = wf_p[0];
    const float out_zero = 1.0f - 0.5f * wf;   // fm == 0 path
    const float4 s4 = sal_sm[hw4];

    fx4* __restrict__ ob =
        (fx4*)(out + (size_t)b * C * HW) + tile * 16 + hw4;

    #pragma unroll 4
    for (int k = 0; k < 32; ++k) {
        const int co = c0 + k;                 // each c-group covers its 32 co's
        const float wc = w[co];
        fx4 r;
        float fm;
        fm = s4.x * wc;
        r.x = (fm > TH) ? 1.0f - wf / (1.0f + __expf(-scale * fm)) : out_zero;
        fm = s4.y * wc;
        r.y = (fm > TH) ? 1.0f - wf / (1.0f + __expf(-scale * fm)) : out_zero;
        fm = s4.z * wc;
        r.z = (fm > TH) ? 1.0f - wf / (1.0f + __expf(-scale * fm)) : out_zero;
        fm = s4.w * wc;
        r.w = (fm > TH) ? 1.0f - wf / (1.0f + __expf(-scale * fm)) : out_zero;
        __builtin_nontemporal_store(r, ob + (size_t)co * HW4);
    }
}

extern "C" void kernel_launch(void* const* d_in, const int* in_sizes, int n_in,
                              void* d_out, int out_size, void* d_ws, size_t ws_size,
                              hipStream_t stream) {
    const float* x      = (const float*)d_in[0];
    const float* conv_w = (const float*)d_in[1];   // 512 floats
    const float* scale  = (const float*)d_in[2];
    const float* wf     = (const float*)d_in[3];
    float* out   = (float*)d_out;
    float* alpha = (float*)d_ws;                   // B*C floats = 64 KB

    alpha_kernel<<<B * C, 256, 0, stream>>>(x, alpha);

    dim3 grid2(HW4 / 16, B);                       // 49 x 32 = 1568 blocks
    fused_kernel<<<grid2, 256, 0, stream>>>(x, alpha, conv_w, scale, wf, out);
}

// Round 5
// 88.290 us; speedup vs baseline: 1.4150x; 1.2106x over previous
//
#include <hip/hip_runtime.h>
#include <hip/hip_bf16.h>

#define B 32
#define C 512
#define HW 3136            // 56*56
#define HW4 784            // float4 columns per plane
#define TH 0.01f
#define CPB 16             // channels per block (kernel A)
#define CPW 4              // channels per wave
#define NPG 32             // partial groups = C/CPB

typedef float fx4 __attribute__((ext_vector_type(4)));

// ---------------------------------------------------------------------------
// Kernel A: single-pass partial saliency.
// Block = (b, cg) of 4 waves; each wave owns 4 channels. Per channel:
// lanes load the whole plane into regs (12-13 fx4/lane, nontemporal),
// in-wave shfl reduce -> alpha, then FMA the SAME regs into acc.
// x is read from HBM exactly once, no barriers inside the c-loop.
// Block partial (sum over its 16 channels) written into d_out plane co=cg.
// ---------------------------------------------------------------------------
__global__ __launch_bounds__(256, 4) void partial_kernel(const float* __restrict__ x,
                                                         float* __restrict__ out) {
    const int b  = blockIdx.y;
    const int cg = blockIdx.x;          // 0..NPG-1
    const int t  = threadIdx.x;
    const int l  = t & 63;
    const int w  = t >> 6;

    const fx4* __restrict__ xb = (const fx4*)(x + (size_t)b * C * HW);

    fx4 acc[13];
    #pragma unroll
    for (int j = 0; j < 13; ++j) acc[j] = (fx4)0.f;

    const int cbase = cg * CPB + w * CPW;
    for (int i = 0; i < CPW; ++i) {
        const fx4* __restrict__ p = xb + (size_t)(cbase + i) * HW4;
        fx4 v[13];
        #pragma unroll
        for (int j = 0; j < 12; ++j) v[j] = __builtin_nontemporal_load(p + l + 64 * j);
        if (l < 16) v[12] = __builtin_nontemporal_load(p + l + 768);

        float s = 0.f;
        #pragma unroll
        for (int j = 0; j < 12; ++j) s += (v[j].x + v[j].y) + (v[j].z + v[j].w);
        if (l < 16) s += (v[12].x + v[12].y) + (v[12].z + v[12].w);
        #pragma unroll
        for (int off = 1; off < 64; off <<= 1) s += __shfl_xor(s, off);
        const float a = s * (1.0f / (float)HW);   // alpha[b,c]

        #pragma unroll
        for (int j = 0; j < 12; ++j) acc[j] += v[j] * a;
        if (l < 16) acc[12] += v[12] * a;
    }

    // cross-wave reduce: waves 1..3 dump acc to LDS, wave 0 sums and writes.
    __shared__ fx4 lds[3][HW4];        // 37,632 B
    if (w > 0) {
        #pragma unroll
        for (int j = 0; j < 12; ++j) lds[w - 1][l + 64 * j] = acc[j];
        if (l < 16) lds[w - 1][l + 768] = acc[12];
    }
    __syncthreads();
    if (w == 0) {
        fx4* __restrict__ dst = (fx4*)(out + (size_t)b * C * HW) + (size_t)cg * HW4;
        #pragma unroll
        for (int j = 0; j < 12; ++j) {
            const int col = l + 64 * j;
            dst[col] = ((acc[j] + lds[0][col]) + (lds[1][col] + lds[2][col]));
        }
        if (l < 16) {
            const int col = l + 768;
            dst[col] = ((acc[12] + lds[0][col]) + (lds[1][col] + lds[2][col]));
        }
    }
}

// ---------------------------------------------------------------------------
// Kernel B: sum 32 partials -> sal, then expansion (same epilogue as R4).
// Block = (b, tile of 16 fx4 cols). Partials live in d_out planes co=0..31,
// read before this block overwrites them (read->sync->write within block).
// ---------------------------------------------------------------------------
__global__ __launch_bounds__(256) void out_kernel(const float* __restrict__ w,
                                                  const float* __restrict__ scale_p,
                                                  const float* __restrict__ wf_p,
                                                  float* __restrict__ out) {
    const int b    = blockIdx.y;
    const int tile = blockIdx.x;               // 0..48
    const int t    = threadIdx.x;
    const int hw4  = t & 15;
    const int pg2  = t >> 4;                   // 0..15 -> partials 2*pg2, 2*pg2+1
    const int lane = t & 63;
    const int wid  = t >> 6;

    const fx4* __restrict__ P =
        (const fx4*)(out + (size_t)b * C * HW) + tile * 16 + hw4;
    fx4 s = P[(size_t)(2 * pg2) * HW4] + P[(size_t)(2 * pg2 + 1) * HW4];

    // reduce the 4 pg2-groups in this wave (lane deltas 16, 32)
    s.x += __shfl_xor(s.x, 16); s.y += __shfl_xor(s.y, 16);
    s.z += __shfl_xor(s.z, 16); s.w += __shfl_xor(s.w, 16);
    s.x += __shfl_xor(s.x, 32); s.y += __shfl_xor(s.y, 32);
    s.z += __shfl_xor(s.z, 32); s.w += __shfl_xor(s.w, 32);

    __shared__ fx4 red[4][16];
    if (lane < 16) red[wid][lane] = s;
    __syncthreads();

    __shared__ fx4 sal_sm[16];
    if (t < 16) {
        sal_sm[t] = ((red[0][t] + red[1][t]) + (red[2][t] + red[3][t])) *
                    (1.0f / (float)C);
    }
    __syncthreads();

    const float scale = scale_p[0];
    const float wf    = wf_p[0];
    const float out_zero = 1.0f - 0.5f * wf;   // fm == 0 path
    const fx4 s4 = sal_sm[hw4];

    fx4* __restrict__ ob = (fx4*)(out + (size_t)b * C * HW) + tile * 16 + hw4;
    const int c0 = pg2 * 32;                   // each group covers its 32 co's

    #pragma unroll 4
    for (int k = 0; k < 32; ++k) {
        const int co = c0 + k;
        const float wc = w[co];
        fx4 r;
        float fm;
        fm = s4.x * wc;
        r.x = (fm > TH) ? 1.0f - wf / (1.0f + __expf(-scale * fm)) : out_zero;
        fm = s4.y * wc;
        r.y = (fm > TH) ? 1.0f - wf / (1.0f + __expf(-scale * fm)) : out_zero;
        fm = s4.z * wc;
        r.z = (fm > TH) ? 1.0f - wf / (1.0f + __expf(-scale * fm)) : out_zero;
        fm = s4.w * wc;
        r.w = (fm > TH) ? 1.0f - wf / (1.0f + __expf(-scale * fm)) : out_zero;
        __builtin_nontemporal_store(r, ob + (size_t)co * HW4);
    }
}

extern "C" void kernel_launch(void* const* d_in, const int* in_sizes, int n_in,
                              void* d_out, int out_size, void* d_ws, size_t ws_size,
                              hipStream_t stream) {
    const float* x      = (const float*)d_in[0];
    const float* conv_w = (const float*)d_in[1];   // 512 floats
    const float* scale  = (const float*)d_in[2];
    const float* wf     = (const float*)d_in[3];
    float* out = (float*)d_out;

    dim3 gridA(NPG, B);                            // 32 x 32 = 1024 blocks
    partial_kernel<<<gridA, 256, 0, stream>>>(x, out);

    dim3 gridB(HW4 / 16, B);                       // 49 x 32 = 1568 blocks
    out_kernel<<<gridB, 256, 0, stream>>>(conv_w, scale, wf, out);
}